// Round 3
// baseline (92.268 us; speedup 1.0000x reference)
//
#include <hip/hip_runtime.h>

// RecurrentFixed_PredPrey: 30 iterations of u = tanh(scalar * (drive + w ⊙ N4-stencil(u)))
// on 32768 independent 16x16 images. W_hidden is the fixed grid adjacency, so we
// never touch it: (u @ Ww.T)[b,i] = w[i] * sum of u over 4-neighbors of pixel i.
//
// Mapping: 1 wave (64 lanes) = 1 image. lane -> (rg = lane>>4, c = lane&15);
// lane owns rows {rg*4+k, k=0..3} of column c in registers.
//   horizontal neighbors: DPP row_shr:1 / row_shl:1 (16-lane DPP row == image row;
//                         bound_ctrl + old=0 zeroes the missing edge neighbor)
//   vertical within strip: registers; across strips: 2 x __shfl(lane +/- 16)/layer
// No LDS, no barriers. tanh via exp2 + rcp (underflow -> exact +/-1 saturation).

namespace {

constexpr int HPIX   = 256;
constexpr int LAYERS = 30;
constexpr int WAVES_PER_BLOCK = 4;

template <int CTRL>
__device__ __forceinline__ float dppf(float x) {
    // old = 0 so invalid source lanes yield 0.0f regardless of bound_ctrl polarity
    int r = __builtin_amdgcn_update_dpp(0, __float_as_int(x), CTRL, 0xF, 0xF, true);
    return __int_as_float(r);
}

__device__ __forceinline__ float tanh_fast(float v, float kneg) {
    // tanh(s*v) = copysign((1 - e)/(1 + e), v),  e = exp2(kneg * |v|), kneg = -2*s*log2(e)
    const float e = __builtin_amdgcn_exp2f(kneg * __builtin_fabsf(v));
    const float t = (1.0f - e) * __builtin_amdgcn_rcpf(1.0f + e);
    return __builtin_copysignf(t, v);
}

__global__ __launch_bounds__(WAVES_PER_BLOCK * 64)
void pp_kernel(const float* __restrict__ X, const float* __restrict__ pred,
               const float* __restrict__ w, const float* __restrict__ av,
               const float* __restrict__ bias, const float* __restrict__ scalar,
               float* __restrict__ out, int nb)
{
    const int lane = threadIdx.x & 63;
    const int img  = blockIdx.x * WAVES_PER_BLOCK + (threadIdx.x >> 6);
    if (img >= nb) return;

    const int rg = lane >> 4;          // row group 0..3 (rows rg*4 .. rg*4+3)
    const int c  = lane & 15;          // column 0..15
    const int p0 = rg * 64 + c;        // pixel index of k=0 row
    const size_t base = (size_t)img * HPIX;

    const float s    = scalar[0];
    const float kneg = -2.0f * s * 1.4426950408889634f;

    float u[4], drv[4], wv[4];
#pragma unroll
    for (int k = 0; k < 4; ++k) {
        const int p = p0 + k * 16;
        const float pr = pred[base + p];
        const float x  = X[base + p];
        const float ufix = (pr == -1.0f) ? 0.0f : pr;   // u_fix
        drv[k] = (ufix + bias[p]) + av[p] * x;          // drive (layer-invariant)
        wv[k]  = w[p];
        u[k]   = pr;                                    // scan carry starts at RAW pred
    }

    const int upLane = (lane - 16) & 63;
    const int dnLane = (lane + 16) & 63;

#pragma unroll 2
    for (int it = 0; it < LAYERS; ++it) {
        // cross-strip vertical exchange
        float top = __shfl(u[3], upLane, 64);   // row rg*4-1 (k=3 of strip above)
        float bot = __shfl(u[0], dnLane, 64);   // row rg*4+4 (k=0 of strip below)
        top = (rg == 0) ? 0.0f : top;
        bot = (rg == 3) ? 0.0f : bot;

        // neighbor sums (read ALL old u before any update)
        float ns0 = (top  + u[1]) + dppf<0x111>(u[0]) + dppf<0x101>(u[0]);
        float ns1 = (u[0] + u[2]) + dppf<0x111>(u[1]) + dppf<0x101>(u[1]);
        float ns2 = (u[1] + u[3]) + dppf<0x111>(u[2]) + dppf<0x101>(u[2]);
        float ns3 = (u[2] + bot ) + dppf<0x111>(u[3]) + dppf<0x101>(u[3]);

        u[0] = tanh_fast(__builtin_fmaf(wv[0], ns0, drv[0]), kneg);
        u[1] = tanh_fast(__builtin_fmaf(wv[1], ns1, drv[1]), kneg);
        u[2] = tanh_fast(__builtin_fmaf(wv[2], ns2, drv[2]), kneg);
        u[3] = tanh_fast(__builtin_fmaf(wv[3], ns3, drv[3]), kneg);
    }

#pragma unroll
    for (int k = 0; k < 4; ++k)
        out[base + p0 + k * 16] = u[k];
}

} // namespace

extern "C" void kernel_launch(void* const* d_in, const int* in_sizes, int n_in,
                              void* d_out, int out_size, void* d_ws, size_t ws_size,
                              hipStream_t stream) {
    // setup_inputs order: X, pred, W_hidden, w, a, bias, scalar
    const float* X      = (const float*)d_in[0];
    const float* pred   = (const float*)d_in[1];
    // d_in[2] = W_hidden: fixed grid adjacency, structure hardcoded in the stencil
    const float* w      = (const float*)d_in[3];
    const float* av     = (const float*)d_in[4];
    const float* bias   = (const float*)d_in[5];
    const float* scalar = (const float*)d_in[6];
    float* out = (float*)d_out;

    const int nb = in_sizes[0] / HPIX;                      // batch rows (32768)
    const int blocks = (nb + WAVES_PER_BLOCK - 1) / WAVES_PER_BLOCK;

    pp_kernel<<<dim3(blocks), dim3(WAVES_PER_BLOCK * 64), 0, stream>>>(
        X, pred, w, av, bias, scalar, out, nb);
}

// Round 4
// 91.775 us; speedup vs baseline: 1.0054x; 1.0054x over previous
//
#include <hip/hip_runtime.h>

// RecurrentFixed_PredPrey: 30 iterations of u = tanh(scalar * (drive + w ⊙ N4-stencil(u)))
// on 32768 independent 16x16 images. W_hidden is the fixed grid adjacency -> stencil.
//
// Layout (R3): 4 images per wave. lane = (g = lane>>4 image-in-wave, r = lane&15 row).
// Each lane owns one full 16-pixel image row in registers u[0..15].
//   horizontal neighbors: in-register (u[c-1] + u[c+1])
//   vertical neighbors:   DPP row_shr:1 / row_shl:1 — the 16-lane DPP row IS the
//                         image (r spans it), so bound_ctrl zeroes top/bottom edges free.
// No LDS, no shuffles, no barriers, no masks in the loop.
// w per row has only 2 distinct values (boundary cols 0/15 vs interior) -> 2 regs.

namespace {

constexpr int HPIX   = 256;
constexpr int LAYERS = 30;
constexpr int WAVES_PER_BLOCK = 4;
constexpr int IMGS_PER_WAVE   = 4;

template <int CTRL>
__device__ __forceinline__ float dppf(float x) {
    // old = 0, bound_ctrl=1: out-of-row source lanes yield 0.0f (image edge)
    int r = __builtin_amdgcn_update_dpp(0, __float_as_int(x), CTRL, 0xF, 0xF, true);
    return __int_as_float(r);
}

__device__ __forceinline__ float tanh_fast(float v, float kneg) {
    // tanh(s*v) = copysign(1 - 2e/(1+e), v),  e = exp2(kneg*|v|), kneg = -2*s*log2(e)
    const float e = __builtin_amdgcn_exp2f(kneg * __builtin_fabsf(v));
    const float rd = __builtin_amdgcn_rcpf(1.0f + e);
    const float t = __builtin_fmaf(e * rd, -2.0f, 1.0f);
    return __builtin_copysignf(t, v);
}

__global__ __launch_bounds__(WAVES_PER_BLOCK * 64)
void pp_kernel(const float* __restrict__ X, const float* __restrict__ pred,
               const float* __restrict__ w, const float* __restrict__ av,
               const float* __restrict__ bias, const float* __restrict__ scalar,
               float* __restrict__ out, int nb)
{
    const int lane = threadIdx.x & 63;
    const int wid  = blockIdx.x * WAVES_PER_BLOCK + (threadIdx.x >> 6);
    const int g    = lane >> 4;                 // image-in-wave 0..3
    const int r    = lane & 15;                 // row 0..15
    const int img  = wid * IMGS_PER_WAVE + g;
    const bool act = (img < nb);
    const int imgc = act ? img : 0;             // clamp for safe loads
    const size_t base = (size_t)imgc * HPIX + r * 16;
    const int    prow = r * 16;                 // per-pixel param row offset

    const float s    = scalar[0];
    const float kneg = -2.0f * s * 1.4426950408889634f;

    float u[16], drv[16];
#pragma unroll
    for (int k = 0; k < 4; ++k) {
        const float4 x4 = *reinterpret_cast<const float4*>(X    + base + k * 4);
        const float4 p4 = *reinterpret_cast<const float4*>(pred + base + k * 4);
        const float4 b4 = *reinterpret_cast<const float4*>(bias + prow + k * 4);
        const float4 a4 = *reinterpret_cast<const float4*>(av   + prow + k * 4);
        const float px[4] = {p4.x, p4.y, p4.z, p4.w};
        const float xx[4] = {x4.x, x4.y, x4.z, x4.w};
        const float bb[4] = {b4.x, b4.y, b4.z, b4.w};
        const float aa[4] = {a4.x, a4.y, a4.z, a4.w};
#pragma unroll
        for (int j = 0; j < 4; ++j) {
            const int c = k * 4 + j;
            const float pr   = px[j];
            const float ufix = (pr == -1.0f) ? 0.0f : pr;            // u_fix
            drv[c] = (ufix + bb[j]) + aa[j] * xx[j];                 // layer-invariant drive
            u[c]   = pr;                                             // scan carry = raw pred
        }
    }
    // w per row: boundary cols (0,15) share one value, interior cols another
    const float wb = w[prow];        // col 0 == col 15 weight for this row
    const float wa = w[prow + 1];    // interior col weight

#pragma unroll 1
    for (int it = 0; it < LAYERS; ++it) {
        float ns[16];
        // horizontal (in-register); image-edge columns have single neighbor
        ns[0]  = u[1];
        ns[15] = u[14];
#pragma unroll
        for (int c = 1; c < 15; ++c) ns[c] = u[c - 1] + u[c + 1];
        // vertical (cross-lane via DPP; bound_ctrl zeroes image top/bottom)
#pragma unroll
        for (int c = 0; c < 16; ++c)
            ns[c] = ns[c] + dppf<0x111>(u[c]) + dppf<0x101>(u[c]);
        // activation
#pragma unroll
        for (int c = 0; c < 16; ++c) {
            const float wc = (c == 0 || c == 15) ? wb : wa;
            u[c] = tanh_fast(__builtin_fmaf(wc, ns[c], drv[c]), kneg);
        }
    }

    if (act) {
#pragma unroll
        for (int k = 0; k < 4; ++k) {
            float4 o4;
            o4.x = u[k * 4 + 0]; o4.y = u[k * 4 + 1];
            o4.z = u[k * 4 + 2]; o4.w = u[k * 4 + 3];
            *reinterpret_cast<float4*>(out + base + k * 4) = o4;
        }
    }
}

} // namespace

extern "C" void kernel_launch(void* const* d_in, const int* in_sizes, int n_in,
                              void* d_out, int out_size, void* d_ws, size_t ws_size,
                              hipStream_t stream) {
    // setup_inputs order: X, pred, W_hidden, w, a, bias, scalar
    const float* X      = (const float*)d_in[0];
    const float* pred   = (const float*)d_in[1];
    // d_in[2] = W_hidden: fixed grid adjacency, hardcoded as the stencil
    const float* w      = (const float*)d_in[3];
    const float* av     = (const float*)d_in[4];
    const float* bias   = (const float*)d_in[5];
    const float* scalar = (const float*)d_in[6];
    float* out = (float*)d_out;

    const int nb = in_sizes[0] / HPIX;  // batch rows (32768)
    const int imgs_per_block = WAVES_PER_BLOCK * IMGS_PER_WAVE;
    const int blocks = (nb + imgs_per_block - 1) / imgs_per_block;

    pp_kernel<<<dim3(blocks), dim3(WAVES_PER_BLOCK * 64), 0, stream>>>(
        X, pred, w, av, bias, scalar, out, nb);
}

// Round 5
// 72.639 us; speedup vs baseline: 1.2702x; 1.2634x over previous
//
#include <hip/hip_runtime.h>

// RecurrentFixed_PredPrey: 30 iterations of u = tanh(scalar * (drive + w ⊙ N4-stencil(u)))
// on 32768 independent 16x16 images. W_hidden is the fixed grid adjacency -> stencil.
//
// Layout (R3): 4 images per wave. lane = (g = lane>>4 image-in-wave, r = lane&15 row).
// Each lane owns one full 16-pixel image row in registers u[0..15].
//   horizontal neighbors: in-register (u[c-1] + u[c+1])
//   vertical neighbors:   DPP row_shr:1 / row_shl:1 — the 16-lane DPP row IS the
//                         image (r spans it), so bound_ctrl zeroes top/bottom edges free.
//
// R4: activation reduced to 3 VALU + 2 trans per pixel:
//   tanh(s*v) = 1 - 2/(exp(2sv)+1)   (sign-correct for both tails, no abs/copysign)
//   argument m = K*(w*ns + drv), K = 2*s*log2(e)  -> pre-scale w,drv by K in prologue:
//   m = fma(w2, ns, drv2); e = exp2(m); r = rcp(e+1); u = fma(r,-2,1)
// No LDS, no shuffles, no barriers, no masks in the loop.

namespace {

constexpr int HPIX   = 256;
constexpr int LAYERS = 30;
constexpr int WAVES_PER_BLOCK = 4;
constexpr int IMGS_PER_WAVE   = 4;

template <int CTRL>
__device__ __forceinline__ float dppf(float x) {
    // old = 0, bound_ctrl=1: out-of-row source lanes yield 0.0f (image edge)
    int r = __builtin_amdgcn_update_dpp(0, __float_as_int(x), CTRL, 0xF, 0xF, true);
    return __int_as_float(r);
}

__global__ __launch_bounds__(WAVES_PER_BLOCK * 64)
void pp_kernel(const float* __restrict__ X, const float* __restrict__ pred,
               const float* __restrict__ w, const float* __restrict__ av,
               const float* __restrict__ bias, const float* __restrict__ scalar,
               float* __restrict__ out, int nb)
{
    const int lane = threadIdx.x & 63;
    const int wid  = blockIdx.x * WAVES_PER_BLOCK + (threadIdx.x >> 6);
    const int g    = lane >> 4;                 // image-in-wave 0..3
    const int r    = lane & 15;                 // row 0..15
    const int img  = wid * IMGS_PER_WAVE + g;
    const bool act = (img < nb);
    const int imgc = act ? img : 0;             // clamp for safe loads
    const size_t base = (size_t)imgc * HPIX + r * 16;
    const int    prow = r * 16;                 // per-pixel param row offset

    const float s = scalar[0];
    const float K = 2.0f * s * 1.4426950408889634f;   // 2*s*log2(e)

    float u[16], drv[16];
#pragma unroll
    for (int k = 0; k < 4; ++k) {
        const float4 x4 = *reinterpret_cast<const float4*>(X    + base + k * 4);
        const float4 p4 = *reinterpret_cast<const float4*>(pred + base + k * 4);
        const float4 b4 = *reinterpret_cast<const float4*>(bias + prow + k * 4);
        const float4 a4 = *reinterpret_cast<const float4*>(av   + prow + k * 4);
        const float px[4] = {p4.x, p4.y, p4.z, p4.w};
        const float xx[4] = {x4.x, x4.y, x4.z, x4.w};
        const float bb[4] = {b4.x, b4.y, b4.z, b4.w};
        const float aa[4] = {a4.x, a4.y, a4.z, a4.w};
#pragma unroll
        for (int j = 0; j < 4; ++j) {
            const int c = k * 4 + j;
            const float pr   = px[j];
            const float ufix = (pr == -1.0f) ? 0.0f : pr;            // u_fix
            drv[c] = K * ((ufix + bb[j]) + aa[j] * xx[j]);           // K-prescaled drive
            u[c]   = pr;                                             // scan carry = raw pred
        }
    }
    // w per row: boundary cols (0,15) share one value, interior cols another (K-prescaled)
    const float w2b = K * w[prow];        // col 0 / col 15 weight for this row
    const float w2a = K * w[prow + 1];    // interior col weight

#pragma unroll 1
    for (int it = 0; it < LAYERS; ++it) {
        float ns[16];
        // horizontal (in-register); image-edge columns have single neighbor
        ns[0]  = u[1];
        ns[15] = u[14];
#pragma unroll
        for (int c = 1; c < 15; ++c) ns[c] = u[c - 1] + u[c + 1];
        // vertical (cross-lane via DPP; bound_ctrl zeroes image top/bottom)
#pragma unroll
        for (int c = 0; c < 16; ++c)
            ns[c] = ns[c] + dppf<0x111>(u[c]) + dppf<0x101>(u[c]);
        // activation: tanh(s*v) = 1 - 2/(exp2(K*v)+1), m = fma(w2, ns, drv2)
#pragma unroll
        for (int c = 0; c < 16; ++c) {
            const float wc = (c == 0 || c == 15) ? w2b : w2a;
            const float m  = __builtin_fmaf(wc, ns[c], drv[c]);
            const float e  = __builtin_amdgcn_exp2f(m);
            const float rd = __builtin_amdgcn_rcpf(e + 1.0f);
            u[c] = __builtin_fmaf(rd, -2.0f, 1.0f);
        }
    }

    if (act) {
#pragma unroll
        for (int k = 0; k < 4; ++k) {
            float4 o4;
            o4.x = u[k * 4 + 0]; o4.y = u[k * 4 + 1];
            o4.z = u[k * 4 + 2]; o4.w = u[k * 4 + 3];
            *reinterpret_cast<float4*>(out + base + k * 4) = o4;
        }
    }
}

} // namespace

extern "C" void kernel_launch(void* const* d_in, const int* in_sizes, int n_in,
                              void* d_out, int out_size, void* d_ws, size_t ws_size,
                              hipStream_t stream) {
    // setup_inputs order: X, pred, W_hidden, w, a, bias, scalar
    const float* X      = (const float*)d_in[0];
    const float* pred   = (const float*)d_in[1];
    // d_in[2] = W_hidden: fixed grid adjacency, hardcoded as the stencil
    const float* w      = (const float*)d_in[3];
    const float* av     = (const float*)d_in[4];
    const float* bias   = (const float*)d_in[5];
    const float* scalar = (const float*)d_in[6];
    float* out = (float*)d_out;

    const int nb = in_sizes[0] / HPIX;  // batch rows (32768)
    const int imgs_per_block = WAVES_PER_BLOCK * IMGS_PER_WAVE;
    const int blocks = (nb + imgs_per_block - 1) / imgs_per_block;

    pp_kernel<<<dim3(blocks), dim3(WAVES_PER_BLOCK * 64), 0, stream>>>(
        X, pred, w, av, bias, scalar, out, nb);
}